// Round 1
// baseline (539.635 us; speedup 1.0000x reference)
//
#include <hip/hip_runtime.h>
#include <math.h>

typedef _Float16 half_t;
typedef _Float16 half8 __attribute__((ext_vector_type(8)));
typedef _Float16 half4_t __attribute__((ext_vector_type(4)));
typedef _Float16 half2_t __attribute__((ext_vector_type(2)));
typedef float floatx4 __attribute__((ext_vector_type(4)));

#define M_TOK 512
#define N_DIM 2048
#define D_HEAD 128
#define H_HEADS 16
#define L_CACHE 4096
#define THREE_N 6144

// ---------------------------------------------------------------------------
// Kernel 1: convert cache_K fp32 [H,L,D] -> fp16 [H,L,D] (same layout)
// ---------------------------------------------------------------------------
__global__ __launch_bounds__(256) void convert_k_kernel(const float* __restrict__ cK,
                                                        half_t* __restrict__ K16) {
    size_t i = ((size_t)blockIdx.x * 256 + threadIdx.x) * 4;
    float4 v = *(const float4*)(cK + i);
    half4_t h = {(half_t)v.x, (half_t)v.y, (half_t)v.z, (half_t)v.w};
    *(half4_t*)(K16 + i) = h;
}

// ---------------------------------------------------------------------------
// Kernel 2: transpose cache_V fp32 [H,L,D] -> fp16 [H,D,L]
// block handles a 32(l) x 32(d) tile of one head. grid = H * (L/32) * (D/32)
// ---------------------------------------------------------------------------
__global__ __launch_bounds__(256) void transpose_v_kernel(const float* __restrict__ cV,
                                                          half_t* __restrict__ V16T) {
    __shared__ half_t tile[32 * 36];  // pad 36 to break bank conflicts
    int b = blockIdx.x;
    int h = b >> 9;            // 512 tiles per head (128 l-tiles * 4 d-tiles)
    int rem = b & 511;
    int lt = rem >> 2, dt = rem & 3;
    int l0 = lt * 32, d0 = dt * 32;
    int t = threadIdx.x;
    {
        int li = t >> 3, c4 = (t & 7) * 4;
        float4 v = *(const float4*)(cV + ((size_t)h * L_CACHE + l0 + li) * D_HEAD + d0 + c4);
        tile[li * 36 + c4 + 0] = (half_t)v.x;
        tile[li * 36 + c4 + 1] = (half_t)v.y;
        tile[li * 36 + c4 + 2] = (half_t)v.z;
        tile[li * 36 + c4 + 3] = (half_t)v.w;
    }
    __syncthreads();
    {
        int di = t >> 3, lj = (t & 7) * 4;
        half4_t o = {tile[(lj + 0) * 36 + di], tile[(lj + 1) * 36 + di],
                     tile[(lj + 2) * 36 + di], tile[(lj + 3) * 36 + di]};
        *(half4_t*)(V16T + ((size_t)h * D_HEAD + d0 + di) * L_CACHE + l0 + lj) = o;
    }
}

// ---------------------------------------------------------------------------
// Kernel 3: qkv[512,6144] = X[512,2048] @ W[2048,6144], f16 MFMA, fp32 out.
// 128x128 tile, BK=32, 256 threads (4 waves in 2x2, each 64x64 = 4x4 MFMA tiles)
// fp32->fp16 conversion fused into LDS staging; W transposed in LDS.
// ---------------------------------------------------------------------------
__global__ __launch_bounds__(256) void gemm_qkv_kernel(const float* __restrict__ X,
                                                       const float* __restrict__ W,
                                                       float* __restrict__ qkv) {
    __shared__ half_t As[128 * 40];  // [m][k] pad 40
    __shared__ half_t Bs[128 * 40];  // [n][k] pad 40 (transposed W tile)
    const int t = threadIdx.x;
    const int wid = t >> 6, lane = t & 63;
    const int quad = lane >> 4, ln = lane & 15;
    const int m0 = blockIdx.y * 128, n0 = blockIdx.x * 128;
    const int wm = (wid >> 1) * 64, wn = (wid & 1) * 64;

    floatx4 acc[4][4] = {};

    for (int k0 = 0; k0 < N_DIM; k0 += 32) {
        __syncthreads();
        // stage A: X tile 128 x 32, convert to f16
        {
            int r = t >> 3, c4 = (t & 7) * 4;
#pragma unroll
            for (int p = 0; p < 4; ++p, r += 32) {
                float4 x = *(const float4*)(X + (size_t)(m0 + r) * N_DIM + k0 + c4);
                half4_t hx = {(half_t)x.x, (half_t)x.y, (half_t)x.z, (half_t)x.w};
                *(half4_t*)&As[r * 40 + c4] = hx;
            }
        }
        // stage B transposed: W tile 32(k) x 128(n) -> Bs[n][k]
        {
            int kr = t >> 5, c4 = (t & 31) * 4;
#pragma unroll
            for (int p = 0; p < 4; ++p, kr += 8) {
                float4 wv = *(const float4*)(W + (size_t)(k0 + kr) * THREE_N + n0 + c4);
                Bs[(c4 + 0) * 40 + kr] = (half_t)wv.x;
                Bs[(c4 + 1) * 40 + kr] = (half_t)wv.y;
                Bs[(c4 + 2) * 40 + kr] = (half_t)wv.z;
                Bs[(c4 + 3) * 40 + kr] = (half_t)wv.w;
            }
        }
        __syncthreads();
        half8 a[4], b[4];
#pragma unroll
        for (int i = 0; i < 4; ++i)
            a[i] = *(half8*)&As[(wm + i * 16 + ln) * 40 + quad * 8];
#pragma unroll
        for (int j = 0; j < 4; ++j)
            b[j] = *(half8*)&Bs[(wn + j * 16 + ln) * 40 + quad * 8];
#pragma unroll
        for (int i = 0; i < 4; ++i)
#pragma unroll
            for (int j = 0; j < 4; ++j)
                acc[i][j] = __builtin_amdgcn_mfma_f32_16x16x32_f16(a[i], b[j], acc[i][j], 0, 0, 0);
    }
#pragma unroll
    for (int i = 0; i < 4; ++i) {
        int row = m0 + wm + i * 16 + quad * 4;
#pragma unroll
        for (int j = 0; j < 4; ++j) {
            int col = n0 + wn + j * 16 + ln;
#pragma unroll
            for (int r = 0; r < 4; ++r)
                qkv[(size_t)(row + r) * THREE_N + col] = acc[i][j][r];
        }
    }
}

// ---------------------------------------------------------------------------
// Kernel 4: per (m,h): RMS-norm q,k; write Q16[h][m][d], K16[h][P+m][d],
// V16T[h][d][P+m]. One wave per (m,h). grid = H*M/4 blocks of 256.
// ---------------------------------------------------------------------------
__global__ __launch_bounds__(256) void norm_scatter_kernel(const float* __restrict__ qkv,
                                                           const int* __restrict__ Pp,
                                                           half_t* __restrict__ Q16,
                                                           half_t* __restrict__ K16,
                                                           half_t* __restrict__ V16T) {
    int gw = blockIdx.x * 4 + (threadIdx.x >> 6);
    int lane = threadIdx.x & 63;
    int h = gw & 15, m = gw >> 4;
    int P = *Pp;
    const float* base = qkv + (size_t)m * THREE_N + h * D_HEAD;
    int d = lane * 2;

    // q
    float q0 = base[d], q1 = base[d + 1];
    float ss = q0 * q0 + q1 * q1;
#pragma unroll
    for (int msk = 32; msk; msk >>= 1) ss += __shfl_xor(ss, msk, 64);
    float sc = rsqrtf(ss * (1.0f / 128.0f));
    half2_t hq = {(half_t)(q0 * sc), (half_t)(q1 * sc)};
    *(half2_t*)(Q16 + ((size_t)h * M_TOK + m) * D_HEAD + d) = hq;

    // k
    float k0 = base[N_DIM + d], k1 = base[N_DIM + d + 1];
    ss = k0 * k0 + k1 * k1;
#pragma unroll
    for (int msk = 32; msk; msk >>= 1) ss += __shfl_xor(ss, msk, 64);
    sc = rsqrtf(ss * (1.0f / 128.0f));
    half2_t hk = {(half_t)(k0 * sc), (half_t)(k1 * sc)};
    *(half2_t*)(K16 + ((size_t)h * L_CACHE + P + m) * D_HEAD + d) = hk;

    // v (no norm), scatter transposed
    float v0 = base[2 * N_DIM + d], v1 = base[2 * N_DIM + d + 1];
    V16T[((size_t)h * D_HEAD + d) * L_CACHE + P + m] = (half_t)v0;
    V16T[((size_t)h * D_HEAD + d + 1) * L_CACHE + P + m] = (half_t)v1;
}

// ---------------------------------------------------------------------------
// Kernel 5: flash attention. grid (M/64, H), 256 threads = 4 waves, each wave
// owns a 16-row m-strip. Online softmax (max-subtracted; mathematically
// identical to reference exp/sum). f16 MFMA 16x16x32.
// ---------------------------------------------------------------------------
__global__ __launch_bounds__(256) void attn_kernel(const half_t* __restrict__ Q16,
                                                   const half_t* __restrict__ K16,
                                                   const half_t* __restrict__ V16T,
                                                   float* __restrict__ out) {
    __shared__ half_t Ks[64 * 136];      // [l][d] pad 136
    __shared__ half_t Vs[128 * 72];      // [d][l] pad 72
    __shared__ half_t Ps[4 * 16 * 72];   // per-wave P tile [m][l] pad 72
    const int t = threadIdx.x, w = t >> 6, lane = t & 63;
    const int quad = lane >> 4, ln = lane & 15;
    const int h = blockIdx.y;
    const int m0 = blockIdx.x * 64 + w * 16;
    const half_t* Qh = Q16 + (size_t)h * M_TOK * D_HEAD;
    const half_t* Kh = K16 + (size_t)h * L_CACHE * D_HEAD;
    const half_t* Vh = V16T + (size_t)h * D_HEAD * L_CACHE;

    half8 qf[4];
#pragma unroll
    for (int dt = 0; dt < 4; ++dt)
        qf[dt] = *(const half8*)(Qh + (size_t)(m0 + ln) * D_HEAD + dt * 32 + quad * 8);

    floatx4 oacc[8] = {};
    float mrow[4], lrow[4];
#pragma unroll
    for (int r = 0; r < 4; ++r) { mrow[r] = -INFINITY; lrow[r] = 0.f; }

    half_t* Pw = Ps + w * (16 * 72);

    for (int l0 = 0; l0 < L_CACHE; l0 += 64) {
        __syncthreads();
        // stage K tile 64(l) x 128(d)
        {
            int lr = t >> 4, ch = t & 15;
#pragma unroll
            for (int p = 0; p < 4; ++p, lr += 16)
                *(half8*)&Ks[lr * 136 + ch * 8] =
                    *(const half8*)(Kh + (size_t)(l0 + lr) * D_HEAD + ch * 8);
        }
        // stage V tile 128(d) x 64(l)
        {
            int dr = t >> 3, ch = t & 7;
#pragma unroll
            for (int p = 0; p < 4; ++p, dr += 32)
                *(half8*)&Vs[dr * 72 + ch * 8] =
                    *(const half8*)(Vh + (size_t)dr * L_CACHE + l0 + ch * 8);
        }
        __syncthreads();

        // S[16][64] = Q K^T
        floatx4 sacc[4] = {};
#pragma unroll
        for (int nt = 0; nt < 4; ++nt)
#pragma unroll
            for (int dt = 0; dt < 4; ++dt) {
                half8 b = *(half8*)&Ks[(nt * 16 + ln) * 136 + dt * 32 + quad * 8];
                sacc[nt] = __builtin_amdgcn_mfma_f32_16x16x32_f16(qf[dt], b, sacc[nt], 0, 0, 0);
            }

        // online softmax per row
        float alpha[4];
#pragma unroll
        for (int r = 0; r < 4; ++r) {
            float mx = fmaxf(fmaxf(sacc[0][r], sacc[1][r]), fmaxf(sacc[2][r], sacc[3][r]));
#pragma unroll
            for (int msk = 8; msk; msk >>= 1) mx = fmaxf(mx, __shfl_xor(mx, msk, 16));
            float mnew = fmaxf(mrow[r], mx);
            alpha[r] = __expf(mrow[r] - mnew);
            mrow[r] = mnew;
            float psum = 0.f;
#pragma unroll
            for (int nt = 0; nt < 4; ++nt) {
                float p = __expf(sacc[nt][r] - mnew);
                sacc[nt][r] = p;
                psum += p;
            }
#pragma unroll
            for (int msk = 8; msk; msk >>= 1) psum += __shfl_xor(psum, msk, 16);
            lrow[r] = lrow[r] * alpha[r] + psum;
        }

        // P -> per-wave LDS (row-major [m][l]) for A-operand reload
#pragma unroll
        for (int nt = 0; nt < 4; ++nt)
#pragma unroll
            for (int r = 0; r < 4; ++r)
                Pw[(quad * 4 + r) * 72 + nt * 16 + ln] = (half_t)sacc[nt][r];

        // rescale O
#pragma unroll
        for (int nt8 = 0; nt8 < 8; ++nt8)
#pragma unroll
            for (int r = 0; r < 4; ++r)
                oacc[nt8][r] *= alpha[r];

        // O += P @ V
#pragma unroll
        for (int kt = 0; kt < 2; ++kt) {
            half8 a = *(half8*)&Pw[ln * 72 + kt * 32 + quad * 8];
#pragma unroll
            for (int nt8 = 0; nt8 < 8; ++nt8) {
                half8 b = *(half8*)&Vs[(nt8 * 16 + ln) * 72 + kt * 32 + quad * 8];
                oacc[nt8] = __builtin_amdgcn_mfma_f32_16x16x32_f16(a, b, oacc[nt8], 0, 0, 0);
            }
        }
    }

    // epilogue: out[m][h*128 + d] = O / l
#pragma unroll
    for (int nt8 = 0; nt8 < 8; ++nt8) {
        int col = h * D_HEAD + nt8 * 16 + ln;
#pragma unroll
        for (int r = 0; r < 4; ++r) {
            int row = m0 + quad * 4 + r;
            out[(size_t)row * N_DIM + col] = oacc[nt8][r] / lrow[r];
        }
    }
}

// ---------------------------------------------------------------------------
extern "C" void kernel_launch(void* const* d_in, const int* in_sizes, int n_in,
                              void* d_out, int out_size, void* d_ws, size_t ws_size,
                              hipStream_t stream) {
    const float* X = (const float*)d_in[0];
    const float* W = (const float*)d_in[1];
    const float* cK = (const float*)d_in[2];
    const float* cV = (const float*)d_in[3];
    const int* Pp = (const int*)d_in[4];
    float* out = (float*)d_out;

    char* ws = (char*)d_ws;
    // workspace layout (bytes):
    //   qkv fp32 : 512*6144*4      = 12,582,912   @ 0
    //   Q16 fp16 : 16*512*128*2    =  2,097,152   @ 12,583,168
    //   K16 fp16 : 16*4096*128*2   = 16,777,216   @ 14,680,320
    //   V16T fp16: 16*128*4096*2   = 16,777,216   @ 31,457,536
    float* qkv = (float*)ws;
    half_t* Q16 = (half_t*)(ws + 12583168);
    half_t* K16 = (half_t*)(ws + 14680320);
    half_t* V16T = (half_t*)(ws + 31457536);

    convert_k_kernel<<<8192, 256, 0, stream>>>(cK, K16);
    transpose_v_kernel<<<8192, 256, 0, stream>>>(cV, V16T);
    gemm_qkv_kernel<<<dim3(48, 4), 256, 0, stream>>>(X, W, qkv);
    norm_scatter_kernel<<<2048, 256, 0, stream>>>(qkv, Pp, Q16, K16, V16T);
    attn_kernel<<<dim3(8, 16), 256, 0, stream>>>(Q16, K16, V16T, out);
}

// Round 2
// 297.213 us; speedup vs baseline: 1.8157x; 1.8157x over previous
//
#include <hip/hip_runtime.h>
#include <math.h>

typedef _Float16 half_t;
typedef _Float16 half8 __attribute__((ext_vector_type(8)));
typedef _Float16 half4_t __attribute__((ext_vector_type(4)));
typedef _Float16 half2_t __attribute__((ext_vector_type(2)));
typedef float floatx4 __attribute__((ext_vector_type(4)));

#define M_TOK 512
#define N_DIM 2048
#define D_HEAD 128
#define H_HEADS 16
#define L_CACHE 4096
#define THREE_N 6144
#define NCHUNK 8
#define LCHUNK 512

// ---------------------------------------------------------------------------
// Kernel 1: convert cache_K fp32 [H,L,D] -> fp16 [H,L,D] (same layout)
// ---------------------------------------------------------------------------
__global__ __launch_bounds__(256) void convert_k_kernel(const float* __restrict__ cK,
                                                        half_t* __restrict__ K16) {
    size_t i = ((size_t)blockIdx.x * 256 + threadIdx.x) * 4;
    float4 v = *(const float4*)(cK + i);
    half4_t h = {(half_t)v.x, (half_t)v.y, (half_t)v.z, (half_t)v.w};
    *(half4_t*)(K16 + i) = h;
}

// ---------------------------------------------------------------------------
// Kernel 2: transpose cache_V fp32 [H,L,D] -> fp16 [H,D,L]
// ---------------------------------------------------------------------------
__global__ __launch_bounds__(256) void transpose_v_kernel(const float* __restrict__ cV,
                                                          half_t* __restrict__ V16T) {
    __shared__ half_t tile[32 * 36];
    int b = blockIdx.x;
    int h = b >> 9;
    int rem = b & 511;
    int lt = rem >> 2, dt = rem & 3;
    int l0 = lt * 32, d0 = dt * 32;
    int t = threadIdx.x;
    {
        int li = t >> 3, c4 = (t & 7) * 4;
        float4 v = *(const float4*)(cV + ((size_t)h * L_CACHE + l0 + li) * D_HEAD + d0 + c4);
        tile[li * 36 + c4 + 0] = (half_t)v.x;
        tile[li * 36 + c4 + 1] = (half_t)v.y;
        tile[li * 36 + c4 + 2] = (half_t)v.z;
        tile[li * 36 + c4 + 3] = (half_t)v.w;
    }
    __syncthreads();
    {
        int di = t >> 3, lj = (t & 7) * 4;
        half4_t o = {tile[(lj + 0) * 36 + di], tile[(lj + 1) * 36 + di],
                     tile[(lj + 2) * 36 + di], tile[(lj + 3) * 36 + di]};
        *(half4_t*)(V16T + ((size_t)h * D_HEAD + d0 + di) * L_CACHE + l0 + lj) = o;
    }
}

// ---------------------------------------------------------------------------
// Kernel 2b: convert X fp32 [512,2048] -> fp16
// ---------------------------------------------------------------------------
__global__ __launch_bounds__(256) void convert_x_kernel(const float* __restrict__ X,
                                                        half_t* __restrict__ X16) {
    size_t i = ((size_t)blockIdx.x * 256 + threadIdx.x) * 4;
    float4 v = *(const float4*)(X + i);
    half4_t h = {(half_t)v.x, (half_t)v.y, (half_t)v.z, (half_t)v.w};
    *(half4_t*)(X16 + i) = h;
}

// ---------------------------------------------------------------------------
// Kernel 2c: transpose+convert W fp32 [2048,6144] -> fp16 W16T [6144,2048]
// grid (192 n-tiles, 64 k-tiles), 32x32 tiles
// ---------------------------------------------------------------------------
__global__ __launch_bounds__(256) void transpose_w_kernel(const float* __restrict__ W,
                                                          half_t* __restrict__ W16T) {
    __shared__ half_t tile[32 * 36];
    int n0 = blockIdx.x * 32, k0 = blockIdx.y * 32;
    int t = threadIdx.x;
    {
        int ki = t >> 3, n4 = (t & 7) * 4;
        float4 v = *(const float4*)(W + (size_t)(k0 + ki) * THREE_N + n0 + n4);
        tile[ki * 36 + n4 + 0] = (half_t)v.x;
        tile[ki * 36 + n4 + 1] = (half_t)v.y;
        tile[ki * 36 + n4 + 2] = (half_t)v.z;
        tile[ki * 36 + n4 + 3] = (half_t)v.w;
    }
    __syncthreads();
    {
        int ni = t >> 3, k4 = (t & 7) * 4;
        half4_t o = {tile[(k4 + 0) * 36 + ni], tile[(k4 + 1) * 36 + ni],
                     tile[(k4 + 2) * 36 + ni], tile[(k4 + 3) * 36 + ni]};
        *(half4_t*)(W16T + (size_t)(n0 + ni) * N_DIM + k0 + k4) = o;
    }
}

// ---------------------------------------------------------------------------
// Kernel 3: qkv[512,6144] = X16 @ W16T^T, f16 MFMA, fp32 out.
// 128x128 tile, BK=32, both operands pre-converted fp16; staging is pure
// vectorized half8 copies (no transpose, no convert in-loop).
// ---------------------------------------------------------------------------
__global__ __launch_bounds__(256) void gemm_qkv_kernel(const half_t* __restrict__ X16,
                                                       const half_t* __restrict__ W16T,
                                                       float* __restrict__ qkv) {
    __shared__ half_t As[128 * 40];  // [m][k] pad 40
    __shared__ half_t Bs[128 * 40];  // [n][k] pad 40
    const int t = threadIdx.x;
    const int wid = t >> 6, lane = t & 63;
    const int quad = lane >> 4, ln = lane & 15;
    const int m0 = blockIdx.y * 128, n0 = blockIdx.x * 128;
    const int wm = (wid >> 1) * 64, wn = (wid & 1) * 64;

    const int srow = t >> 2, sgrp = (t & 3) * 8;

    floatx4 acc[4][4] = {};

    for (int k0 = 0; k0 < N_DIM; k0 += 32) {
        __syncthreads();
#pragma unroll
        for (int p = 0; p < 2; ++p) {
            int r = srow + p * 64;
            *(half8*)&As[r * 40 + sgrp] =
                *(const half8*)(X16 + (size_t)(m0 + r) * N_DIM + k0 + sgrp);
            *(half8*)&Bs[r * 40 + sgrp] =
                *(const half8*)(W16T + (size_t)(n0 + r) * N_DIM + k0 + sgrp);
        }
        __syncthreads();
        half8 a[4], b[4];
#pragma unroll
        for (int i = 0; i < 4; ++i)
            a[i] = *(half8*)&As[(wm + i * 16 + ln) * 40 + quad * 8];
#pragma unroll
        for (int j = 0; j < 4; ++j)
            b[j] = *(half8*)&Bs[(wn + j * 16 + ln) * 40 + quad * 8];
#pragma unroll
        for (int i = 0; i < 4; ++i)
#pragma unroll
            for (int j = 0; j < 4; ++j)
                acc[i][j] = __builtin_amdgcn_mfma_f32_16x16x32_f16(a[i], b[j], acc[i][j], 0, 0, 0);
    }
#pragma unroll
    for (int i = 0; i < 4; ++i) {
        int row = m0 + wm + i * 16 + quad * 4;
#pragma unroll
        for (int j = 0; j < 4; ++j) {
            int col = n0 + wn + j * 16 + ln;
#pragma unroll
            for (int r = 0; r < 4; ++r)
                qkv[(size_t)(row + r) * THREE_N + col] = acc[i][j][r];
        }
    }
}

// ---------------------------------------------------------------------------
// Kernel 4: per (m,h): RMS-norm q,k; write Q16[h][m][d], K16[h][P+m][d],
// V16T[h][d][P+m]. One wave per (m,h).
// ---------------------------------------------------------------------------
__global__ __launch_bounds__(256) void norm_scatter_kernel(const float* __restrict__ qkv,
                                                           const int* __restrict__ Pp,
                                                           half_t* __restrict__ Q16,
                                                           half_t* __restrict__ K16,
                                                           half_t* __restrict__ V16T) {
    int gw = blockIdx.x * 4 + (threadIdx.x >> 6);
    int lane = threadIdx.x & 63;
    int h = gw & 15, m = gw >> 4;
    int P = *Pp;
    const float* base = qkv + (size_t)m * THREE_N + h * D_HEAD;
    int d = lane * 2;

    float q0 = base[d], q1 = base[d + 1];
    float ss = q0 * q0 + q1 * q1;
#pragma unroll
    for (int msk = 32; msk; msk >>= 1) ss += __shfl_xor(ss, msk, 64);
    float sc = rsqrtf(ss * (1.0f / 128.0f));
    half2_t hq = {(half_t)(q0 * sc), (half_t)(q1 * sc)};
    *(half2_t*)(Q16 + ((size_t)h * M_TOK + m) * D_HEAD + d) = hq;

    float k0 = base[N_DIM + d], k1 = base[N_DIM + d + 1];
    ss = k0 * k0 + k1 * k1;
#pragma unroll
    for (int msk = 32; msk; msk >>= 1) ss += __shfl_xor(ss, msk, 64);
    sc = rsqrtf(ss * (1.0f / 128.0f));
    half2_t hk = {(half_t)(k0 * sc), (half_t)(k1 * sc)};
    *(half2_t*)(K16 + ((size_t)h * L_CACHE + P + m) * D_HEAD + d) = hk;

    float v0 = base[2 * N_DIM + d], v1 = base[2 * N_DIM + d + 1];
    V16T[((size_t)h * D_HEAD + d) * L_CACHE + P + m] = (half_t)v0;
    V16T[((size_t)h * D_HEAD + d + 1) * L_CACHE + P + m] = (half_t)v1;
}

// ---------------------------------------------------------------------------
// Kernel 5: flash attention over an L-chunk of 512. grid (M/64, H, NCHUNK),
// 256 threads = 4 waves, each wave a 16-row m-strip. Writes unnormalized
// partial O + per-row (m,l) stats; combine kernel merges chunks.
// ---------------------------------------------------------------------------
__global__ __launch_bounds__(256) void attn_partial_kernel(const half_t* __restrict__ Q16,
                                                           const half_t* __restrict__ K16,
                                                           const half_t* __restrict__ V16T,
                                                           float* __restrict__ Opart,
                                                           float* __restrict__ mstat,
                                                           float* __restrict__ lstat) {
    __shared__ half_t Ks[64 * 136];
    __shared__ half_t Vs[128 * 72];
    __shared__ half_t Ps[4 * 16 * 72];
    const int t = threadIdx.x, w = t >> 6, lane = t & 63;
    const int quad = lane >> 4, ln = lane & 15;
    const int h = blockIdx.y, c = blockIdx.z;
    const int m0 = blockIdx.x * 64 + w * 16;
    const half_t* Qh = Q16 + (size_t)h * M_TOK * D_HEAD;
    const half_t* Kh = K16 + (size_t)h * L_CACHE * D_HEAD;
    const half_t* Vh = V16T + (size_t)h * D_HEAD * L_CACHE;

    half8 qf[4];
#pragma unroll
    for (int dt = 0; dt < 4; ++dt)
        qf[dt] = *(const half8*)(Qh + (size_t)(m0 + ln) * D_HEAD + dt * 32 + quad * 8);

    floatx4 oacc[8] = {};
    float mrow[4], lrow[4];
#pragma unroll
    for (int r = 0; r < 4; ++r) { mrow[r] = -INFINITY; lrow[r] = 0.f; }

    half_t* Pw = Ps + w * (16 * 72);

    for (int l0 = c * LCHUNK; l0 < (c + 1) * LCHUNK; l0 += 64) {
        __syncthreads();
        {
            int lr = t >> 4, ch = t & 15;
#pragma unroll
            for (int p = 0; p < 4; ++p, lr += 16)
                *(half8*)&Ks[lr * 136 + ch * 8] =
                    *(const half8*)(Kh + (size_t)(l0 + lr) * D_HEAD + ch * 8);
        }
        {
            int dr = t >> 3, ch = t & 7;
#pragma unroll
            for (int p = 0; p < 4; ++p, dr += 32)
                *(half8*)&Vs[dr * 72 + ch * 8] =
                    *(const half8*)(Vh + (size_t)dr * L_CACHE + l0 + ch * 8);
        }
        __syncthreads();

        floatx4 sacc[4] = {};
#pragma unroll
        for (int nt = 0; nt < 4; ++nt)
#pragma unroll
            for (int dt = 0; dt < 4; ++dt) {
                half8 b = *(half8*)&Ks[(nt * 16 + ln) * 136 + dt * 32 + quad * 8];
                sacc[nt] = __builtin_amdgcn_mfma_f32_16x16x32_f16(qf[dt], b, sacc[nt], 0, 0, 0);
            }

        float alpha[4];
#pragma unroll
        for (int r = 0; r < 4; ++r) {
            float mx = fmaxf(fmaxf(sacc[0][r], sacc[1][r]), fmaxf(sacc[2][r], sacc[3][r]));
#pragma unroll
            for (int msk = 8; msk; msk >>= 1) mx = fmaxf(mx, __shfl_xor(mx, msk, 16));
            float mnew = fmaxf(mrow[r], mx);
            alpha[r] = __expf(mrow[r] - mnew);
            mrow[r] = mnew;
            float psum = 0.f;
#pragma unroll
            for (int nt = 0; nt < 4; ++nt) {
                float p = __expf(sacc[nt][r] - mnew);
                sacc[nt][r] = p;
                psum += p;
            }
#pragma unroll
            for (int msk = 8; msk; msk >>= 1) psum += __shfl_xor(psum, msk, 16);
            lrow[r] = lrow[r] * alpha[r] + psum;
        }

#pragma unroll
        for (int nt = 0; nt < 4; ++nt)
#pragma unroll
            for (int r = 0; r < 4; ++r)
                Pw[(quad * 4 + r) * 72 + nt * 16 + ln] = (half_t)sacc[nt][r];

#pragma unroll
        for (int nt8 = 0; nt8 < 8; ++nt8)
#pragma unroll
            for (int r = 0; r < 4; ++r)
                oacc[nt8][r] *= alpha[r];

#pragma unroll
        for (int kt = 0; kt < 2; ++kt) {
            half8 a = *(half8*)&Pw[ln * 72 + kt * 32 + quad * 8];
#pragma unroll
            for (int nt8 = 0; nt8 < 8; ++nt8) {
                half8 b = *(half8*)&Vs[(nt8 * 16 + ln) * 72 + kt * 32 + quad * 8];
                oacc[nt8] = __builtin_amdgcn_mfma_f32_16x16x32_f16(a, b, oacc[nt8], 0, 0, 0);
            }
        }
    }

    // epilogue: unnormalized partial O + stats
    float* Oc = Opart + ((size_t)(c * H_HEADS + h) * M_TOK) * D_HEAD;
#pragma unroll
    for (int nt8 = 0; nt8 < 8; ++nt8) {
        int col = nt8 * 16 + ln;
#pragma unroll
        for (int r = 0; r < 4; ++r) {
            int row = m0 + quad * 4 + r;
            Oc[(size_t)row * D_HEAD + col] = oacc[nt8][r];
        }
    }
    if (ln == 0) {
        float* ms = mstat + (size_t)(c * H_HEADS + h) * M_TOK;
        float* ls = lstat + (size_t)(c * H_HEADS + h) * M_TOK;
#pragma unroll
        for (int r = 0; r < 4; ++r) {
            int row = m0 + quad * 4 + r;
            ms[row] = mrow[r];
            ls[row] = lrow[r];
        }
    }
}

// ---------------------------------------------------------------------------
// Kernel 6: combine NCHUNK partials. One wave per (h,m) row.
// ---------------------------------------------------------------------------
__global__ __launch_bounds__(256) void combine_kernel(const float* __restrict__ Opart,
                                                      const float* __restrict__ mstat,
                                                      const float* __restrict__ lstat,
                                                      float* __restrict__ out) {
    int gw = blockIdx.x * 4 + (threadIdx.x >> 6);
    int lane = threadIdx.x & 63;
    int h = gw >> 9, m = gw & 511;
    int d = lane * 2;

    float ms[NCHUNK];
    float mg = -INFINITY;
#pragma unroll
    for (int c = 0; c < NCHUNK; ++c) {
        ms[c] = mstat[((c * H_HEADS + h) << 9) + m];
        mg = fmaxf(mg, ms[c]);
    }
    float denom = 0.f, o0 = 0.f, o1 = 0.f;
#pragma unroll
    for (int c = 0; c < NCHUNK; ++c) {
        float e = __expf(ms[c] - mg);
        denom += lstat[((c * H_HEADS + h) << 9) + m] * e;
        const float* Oc = Opart + (((size_t)(c * H_HEADS + h) << 9) + m) * D_HEAD + d;
        float2 v = *(const float2*)Oc;
        o0 += v.x * e;
        o1 += v.y * e;
    }
    float inv = 1.0f / denom;
    float* op = out + (size_t)m * N_DIM + h * D_HEAD + d;
    op[0] = o0 * inv;
    op[1] = o1 * inv;
}

// ---------------------------------------------------------------------------
extern "C" void kernel_launch(void* const* d_in, const int* in_sizes, int n_in,
                              void* d_out, int out_size, void* d_ws, size_t ws_size,
                              hipStream_t stream) {
    const float* X = (const float*)d_in[0];
    const float* W = (const float*)d_in[1];
    const float* cK = (const float*)d_in[2];
    const float* cV = (const float*)d_in[3];
    const int* Pp = (const int*)d_in[4];
    float* out = (float*)d_out;

    char* ws = (char*)d_ws;
    // workspace layout (bytes):
    //   Q16  @ 0          (2,097,152)
    //   K16  @ 2,097,152  (16,777,216)
    //   V16T @ 18,874,368 (16,777,216)
    //   X16  @ 35,651,584 (2,097,152)
    //   W16T @ 37,748,736 (25,165,824)  [dead after gemm]
    //   qkv  @ 62,914,560 (12,582,912)  [dead after norm_scatter]
    //   Opart@ 37,748,736 (33,554,432)  [overlays W16T+qkv head; written after both dead]
    //   mstat@ 75,497,472 (262,144)
    //   lstat@ 75,759,616 (262,144)
    //   total 76,021,760
    half_t* Q16 = (half_t*)(ws + 0);
    half_t* K16 = (half_t*)(ws + 2097152);
    half_t* V16T = (half_t*)(ws + 18874368);
    half_t* X16 = (half_t*)(ws + 35651584);
    half_t* W16T = (half_t*)(ws + 37748736);
    float* qkv = (float*)(ws + 62914560);
    float* Opart = (float*)(ws + 37748736);
    float* mstat = (float*)(ws + 75497472);
    float* lstat = (float*)(ws + 75759616);

    convert_k_kernel<<<8192, 256, 0, stream>>>(cK, K16);
    transpose_v_kernel<<<8192, 256, 0, stream>>>(cV, V16T);
    convert_x_kernel<<<1024, 256, 0, stream>>>(X, X16);
    transpose_w_kernel<<<dim3(192, 64), 256, 0, stream>>>(W, W16T);
    gemm_qkv_kernel<<<dim3(48, 4), 256, 0, stream>>>(X16, W16T, qkv);
    norm_scatter_kernel<<<2048, 256, 0, stream>>>(qkv, Pp, Q16, K16, V16T);
    attn_partial_kernel<<<dim3(8, 16, 8), 256, 0, stream>>>(Q16, K16, V16T, Opart, mstat, lstat);
    combine_kernel<<<2048, 256, 0, stream>>>(Opart, mstat, lstat, out);
}

// Round 3
// 275.808 us; speedup vs baseline: 1.9566x; 1.0776x over previous
//
#include <hip/hip_runtime.h>
#include <math.h>

typedef _Float16 half_t;
typedef _Float16 half8 __attribute__((ext_vector_type(8)));
typedef _Float16 half4_t __attribute__((ext_vector_type(4)));
typedef float floatx4 __attribute__((ext_vector_type(4)));

#define M_TOK 512
#define N_DIM 2048
#define D_HEAD 128
#define H_HEADS 16
#define L_CACHE 4096
#define THREE_N 6144
#define NCHUNK 8
#define LCHUNK 512

// ---------------------------------------------------------------------------
// Kernel 1: convert cache_K fp32 [H,L,D] -> fp16 [H,L,D]
// ---------------------------------------------------------------------------
__global__ __launch_bounds__(256) void convert_k_kernel(const float* __restrict__ cK,
                                                        half_t* __restrict__ K16) {
    size_t i = ((size_t)blockIdx.x * 256 + threadIdx.x) * 4;
    float4 v = *(const float4*)(cK + i);
    half4_t h = {(half_t)v.x, (half_t)v.y, (half_t)v.z, (half_t)v.w};
    *(half4_t*)(K16 + i) = h;
}

// ---------------------------------------------------------------------------
// Kernel 2: transpose cache_V fp32 [H,L,D] -> fp16 [H,D,L]
// ---------------------------------------------------------------------------
__global__ __launch_bounds__(256) void transpose_v_kernel(const float* __restrict__ cV,
                                                          half_t* __restrict__ V16T) {
    __shared__ half_t tile[32 * 36];
    int b = blockIdx.x;
    int h = b >> 9;
    int rem = b & 511;
    int lt = rem >> 2, dt = rem & 3;
    int l0 = lt * 32, d0 = dt * 32;
    int t = threadIdx.x;
    {
        int li = t >> 3, c4 = (t & 7) * 4;
        float4 v = *(const float4*)(cV + ((size_t)h * L_CACHE + l0 + li) * D_HEAD + d0 + c4);
        tile[li * 36 + c4 + 0] = (half_t)v.x;
        tile[li * 36 + c4 + 1] = (half_t)v.y;
        tile[li * 36 + c4 + 2] = (half_t)v.z;
        tile[li * 36 + c4 + 3] = (half_t)v.w;
    }
    __syncthreads();
    {
        int di = t >> 3, lj = (t & 7) * 4;
        half4_t o = {tile[(lj + 0) * 36 + di], tile[(lj + 1) * 36 + di],
                     tile[(lj + 2) * 36 + di], tile[(lj + 3) * 36 + di]};
        *(half4_t*)(V16T + ((size_t)h * D_HEAD + d0 + di) * L_CACHE + l0 + lj) = o;
    }
}

// ---------------------------------------------------------------------------
// Kernel 3: transpose+convert W fp32 [2048,6144] -> fp16 W16T [6144,2048]
// ---------------------------------------------------------------------------
__global__ __launch_bounds__(256) void transpose_w_kernel(const float* __restrict__ W,
                                                          half_t* __restrict__ W16T) {
    __shared__ half_t tile[32 * 36];
    int n0 = blockIdx.x * 32, k0 = blockIdx.y * 32;
    int t = threadIdx.x;
    {
        int ki = t >> 3, n4 = (t & 7) * 4;
        float4 v = *(const float4*)(W + (size_t)(k0 + ki) * THREE_N + n0 + n4);
        tile[ki * 36 + n4 + 0] = (half_t)v.x;
        tile[ki * 36 + n4 + 1] = (half_t)v.y;
        tile[ki * 36 + n4 + 2] = (half_t)v.z;
        tile[ki * 36 + n4 + 3] = (half_t)v.w;
    }
    __syncthreads();
    {
        int ni = t >> 3, k4 = (t & 7) * 4;
        half4_t o = {tile[(k4 + 0) * 36 + ni], tile[(k4 + 1) * 36 + ni],
                     tile[(k4 + 2) * 36 + ni], tile[(k4 + 3) * 36 + ni]};
        *(half4_t*)(W16T + (size_t)(n0 + ni) * N_DIM + k0 + k4) = o;
    }
}

// ---------------------------------------------------------------------------
// Kernel 4: fused GEMM + RMS-norm + scatter.
// qkv tile = X[64m x 2048] @ W16T[128n x 2048]^T. n-block == one head-segment:
// bx 0..15 -> q head bx, 16..31 -> k head bx-16, 32..47 -> v head bx-32.
// Epilogue: per-row sumsq (shuffle + cross-wave LDS), rsqrt, fp16 write to
// Q16 [H,M,D] / K16 rows P..P+M / Vnew16 [H,M,D]. No qkv buffer.
// ---------------------------------------------------------------------------
__global__ __launch_bounds__(256) void gemm_fused_kernel(const float* __restrict__ X,
                                                         const half_t* __restrict__ W16T,
                                                         const int* __restrict__ Pp,
                                                         half_t* __restrict__ Q16,
                                                         half_t* __restrict__ K16,
                                                         half_t* __restrict__ Vnew16) {
    __shared__ half_t As[64 * 72];   // [m][k] BK=64, pad 72
    __shared__ half_t Bs[128 * 72];  // [n][k]
    __shared__ float ssbuf[4][32];
    const int t = threadIdx.x;
    const int wid = t >> 6, lane = t & 63;
    const int quad = lane >> 4, ln = lane & 15;
    const int bx = blockIdx.x, by = blockIdx.y;
    const int m0 = by * 64, n0 = bx * 128;
    const int wm = (wid >> 1) * 32, wn = (wid & 1) * 64;

    floatx4 acc[2][4] = {};

    const int ar = t >> 4, ac4 = (t & 15) * 4;  // A: 16 rows/pass, 4 passes
    const int br = t >> 3, bg = (t & 7) * 8;    // B: 32 rows/pass, 4 passes

    for (int k0 = 0; k0 < N_DIM; k0 += 64) {
        __syncthreads();
#pragma unroll
        for (int p = 0; p < 4; ++p) {
            int r = ar + p * 16;
            float4 x = *(const float4*)(X + (size_t)(m0 + r) * N_DIM + k0 + ac4);
            half4_t hx = {(half_t)x.x, (half_t)x.y, (half_t)x.z, (half_t)x.w};
            *(half4_t*)&As[r * 72 + ac4] = hx;
        }
#pragma unroll
        for (int p = 0; p < 4; ++p) {
            int r = br + p * 32;
            *(half8*)&Bs[r * 72 + bg] =
                *(const half8*)(W16T + (size_t)(n0 + r) * N_DIM + k0 + bg);
        }
        __syncthreads();
#pragma unroll
        for (int kt = 0; kt < 2; ++kt) {
            half8 a[2], b[4];
#pragma unroll
            for (int i = 0; i < 2; ++i)
                a[i] = *(half8*)&As[(wm + i * 16 + ln) * 72 + kt * 32 + quad * 8];
#pragma unroll
            for (int j = 0; j < 4; ++j)
                b[j] = *(half8*)&Bs[(wn + j * 16 + ln) * 72 + kt * 32 + quad * 8];
#pragma unroll
            for (int i = 0; i < 2; ++i)
#pragma unroll
                for (int j = 0; j < 4; ++j)
                    acc[i][j] = __builtin_amdgcn_mfma_f32_16x16x32_f16(a[i], b[j], acc[i][j], 0, 0, 0);
        }
    }

    const int seg = bx >> 4, h = bx & 15;
    float scale[2][4];
    if (seg < 2) {  // block-uniform branch
        float ss[2][4];
#pragma unroll
        for (int i = 0; i < 2; ++i)
#pragma unroll
            for (int r = 0; r < 4; ++r) {
                float s = 0.f;
#pragma unroll
                for (int j = 0; j < 4; ++j) s += acc[i][j][r] * acc[i][j][r];
#pragma unroll
                for (int msk = 1; msk < 16; msk <<= 1) s += __shfl_xor(s, msk, 64);
                ss[i][r] = s;
            }
        if (ln == 0) {
#pragma unroll
            for (int i = 0; i < 2; ++i)
#pragma unroll
                for (int r = 0; r < 4; ++r)
                    ssbuf[wid][i * 16 + quad * 4 + r] = ss[i][r];
        }
        __syncthreads();
#pragma unroll
        for (int i = 0; i < 2; ++i)
#pragma unroll
            for (int r = 0; r < 4; ++r)
                scale[i][r] =
                    rsqrtf((ss[i][r] + ssbuf[wid ^ 1][i * 16 + quad * 4 + r]) * (1.0f / 128.0f));
    } else {
#pragma unroll
        for (int i = 0; i < 2; ++i)
#pragma unroll
            for (int r = 0; r < 4; ++r) scale[i][r] = 1.0f;
    }

    const int P = *Pp;
#pragma unroll
    for (int i = 0; i < 2; ++i) {
        int mbase = m0 + wm + i * 16 + quad * 4;
#pragma unroll
        for (int j = 0; j < 4; ++j) {
            int col = wn + j * 16 + ln;
#pragma unroll
            for (int r = 0; r < 4; ++r) {
                int m = mbase + r;
                half_t val = (half_t)(acc[i][j][r] * scale[i][r]);
                if (seg == 0)
                    Q16[((size_t)h * M_TOK + m) * D_HEAD + col] = val;
                else if (seg == 1)
                    K16[((size_t)h * L_CACHE + P + m) * D_HEAD + col] = val;
                else
                    Vnew16[((size_t)h * M_TOK + m) * D_HEAD + col] = val;
            }
        }
    }
}

// ---------------------------------------------------------------------------
// Kernel 5: transpose Vnew16 [H,M,D] -> V16T columns P..P+M. 32x32 tiles.
// ---------------------------------------------------------------------------
__global__ __launch_bounds__(256) void transpose_vnew_kernel(const half_t* __restrict__ Vnew16,
                                                             const int* __restrict__ Pp,
                                                             half_t* __restrict__ V16T) {
    __shared__ half_t tile[32 * 36];
    int b = blockIdx.x;
    int h = b >> 6, mt = (b >> 2) & 15, dt = b & 3;
    int m0 = mt * 32, d0 = dt * 32;
    int t = threadIdx.x;
    int P = *Pp;
    {
        int mi = t >> 3, d4 = (t & 7) * 4;
        half4_t v = *(const half4_t*)(Vnew16 + ((size_t)h * M_TOK + m0 + mi) * D_HEAD + d0 + d4);
        *(half4_t*)&tile[mi * 36 + d4] = v;
    }
    __syncthreads();
    {
        int di = t >> 3, m4 = (t & 7) * 4;
#pragma unroll
        for (int u = 0; u < 4; ++u)
            V16T[((size_t)h * D_HEAD + d0 + di) * L_CACHE + P + m0 + m4 + u] =
                tile[(m4 + u) * 36 + di];
    }
}

// ---------------------------------------------------------------------------
// Kernel 6: flash attention partial over L-chunk of 512. grid (4, H, NCHUNK),
// 128 m-rows per block: 4 waves x 2 strips of 16 rows. Online softmax,
// unnormalized partial O + (m,l) stats.
// ---------------------------------------------------------------------------
__global__ __launch_bounds__(256, 2) void attn_partial_kernel(const half_t* __restrict__ Q16,
                                                              const half_t* __restrict__ K16,
                                                              const half_t* __restrict__ V16T,
                                                              float* __restrict__ Opart,
                                                              float* __restrict__ mstat,
                                                              float* __restrict__ lstat) {
    __shared__ half_t Ks[64 * 136];
    __shared__ half_t Vs[128 * 72];
    __shared__ half_t Ps[4 * 16 * 72];  // per-wave, reused across strips
    const int t = threadIdx.x, w = t >> 6, lane = t & 63;
    const int quad = lane >> 4, ln = lane & 15;
    const int h = blockIdx.y, c = blockIdx.z;
    const int mb = blockIdx.x * 128;
    const half_t* Qh = Q16 + (size_t)h * M_TOK * D_HEAD;
    const half_t* Kh = K16 + (size_t)h * L_CACHE * D_HEAD;
    const half_t* Vh = V16T + (size_t)h * D_HEAD * L_CACHE;

    half8 qf[2][4];
#pragma unroll
    for (int s = 0; s < 2; ++s) {
        int m0 = mb + s * 64 + w * 16;
#pragma unroll
        for (int dt = 0; dt < 4; ++dt)
            qf[s][dt] = *(const half8*)(Qh + (size_t)(m0 + ln) * D_HEAD + dt * 32 + quad * 8);
    }

    floatx4 oacc[2][8] = {};
    float mrow[2][4], lrow[2][4];
#pragma unroll
    for (int s = 0; s < 2; ++s)
#pragma unroll
        for (int r = 0; r < 4; ++r) { mrow[s][r] = -INFINITY; lrow[s][r] = 0.f; }

    half_t* Pw = Ps + w * (16 * 72);

    for (int l0 = c * LCHUNK; l0 < (c + 1) * LCHUNK; l0 += 64) {
        __syncthreads();
        {
            int lr = t >> 4, ch = t & 15;
#pragma unroll
            for (int p = 0; p < 4; ++p, lr += 16)
                *(half8*)&Ks[lr * 136 + ch * 8] =
                    *(const half8*)(Kh + (size_t)(l0 + lr) * D_HEAD + ch * 8);
        }
        {
            int dr = t >> 3, ch = t & 7;
#pragma unroll
            for (int p = 0; p < 4; ++p, dr += 32)
                *(half8*)&Vs[dr * 72 + ch * 8] =
                    *(const half8*)(Vh + (size_t)dr * L_CACHE + l0 + ch * 8);
        }
        __syncthreads();

#pragma unroll
        for (int s = 0; s < 2; ++s) {
            floatx4 sacc[4] = {};
#pragma unroll
            for (int nt = 0; nt < 4; ++nt)
#pragma unroll
                for (int dt = 0; dt < 4; ++dt) {
                    half8 b = *(half8*)&Ks[(nt * 16 + ln) * 136 + dt * 32 + quad * 8];
                    sacc[nt] = __builtin_amdgcn_mfma_f32_16x16x32_f16(qf[s][dt], b, sacc[nt], 0, 0, 0);
                }

            float alpha[4];
#pragma unroll
            for (int r = 0; r < 4; ++r) {
                float mx = fmaxf(fmaxf(sacc[0][r], sacc[1][r]), fmaxf(sacc[2][r], sacc[3][r]));
#pragma unroll
                for (int msk = 8; msk; msk >>= 1) mx = fmaxf(mx, __shfl_xor(mx, msk, 16));
                float mnew = fmaxf(mrow[s][r], mx);
                alpha[r] = __expf(mrow[s][r] - mnew);
                mrow[s][r] = mnew;
                float psum = 0.f;
#pragma unroll
                for (int nt = 0; nt < 4; ++nt) {
                    float p = __expf(sacc[nt][r] - mnew);
                    sacc[nt][r] = p;
                    psum += p;
                }
#pragma unroll
                for (int msk = 8; msk; msk >>= 1) psum += __shfl_xor(psum, msk, 16);
                lrow[s][r] = lrow[s][r] * alpha[r] + psum;
            }

#pragma unroll
            for (int nt = 0; nt < 4; ++nt)
#pragma unroll
                for (int r = 0; r < 4; ++r)
                    Pw[(quad * 4 + r) * 72 + nt * 16 + ln] = (half_t)sacc[nt][r];

#pragma unroll
            for (int nt8 = 0; nt8 < 8; ++nt8)
#pragma unroll
                for (int r = 0; r < 4; ++r)
                    oacc[s][nt8][r] *= alpha[r];

#pragma unroll
            for (int kt = 0; kt < 2; ++kt) {
                half8 a = *(half8*)&Pw[ln * 72 + kt * 32 + quad * 8];
#pragma unroll
                for (int nt8 = 0; nt8 < 8; ++nt8) {
                    half8 b = *(half8*)&Vs[(nt8 * 16 + ln) * 72 + kt * 32 + quad * 8];
                    oacc[s][nt8] = __builtin_amdgcn_mfma_f32_16x16x32_f16(a, b, oacc[s][nt8], 0, 0, 0);
                }
            }
        }
    }

    float* Oc = Opart + ((size_t)(c * H_HEADS + h) * M_TOK) * D_HEAD;
    float* ms = mstat + (size_t)(c * H_HEADS + h) * M_TOK;
    float* ls = lstat + (size_t)(c * H_HEADS + h) * M_TOK;
#pragma unroll
    for (int s = 0; s < 2; ++s) {
        int m0 = mb + s * 64 + w * 16;
#pragma unroll
        for (int nt8 = 0; nt8 < 8; ++nt8) {
            int col = nt8 * 16 + ln;
#pragma unroll
            for (int r = 0; r < 4; ++r)
                Oc[(size_t)(m0 + quad * 4 + r) * D_HEAD + col] = oacc[s][nt8][r];
        }
        if (ln == 0) {
#pragma unroll
            for (int r = 0; r < 4; ++r) {
                ms[m0 + quad * 4 + r] = mrow[s][r];
                ls[m0 + quad * 4 + r] = lrow[s][r];
            }
        }
    }
}

// ---------------------------------------------------------------------------
// Kernel 7: combine NCHUNK partials. One wave per (h,m) row.
// ---------------------------------------------------------------------------
__global__ __launch_bounds__(256) void combine_kernel(const float* __restrict__ Opart,
                                                      const float* __restrict__ mstat,
                                                      const float* __restrict__ lstat,
                                                      float* __restrict__ out) {
    int gw = blockIdx.x * 4 + (threadIdx.x >> 6);
    int lane = threadIdx.x & 63;
    int h = gw >> 9, m = gw & 511;
    int d = lane * 2;

    float ms[NCHUNK];
    float mg = -INFINITY;
#pragma unroll
    for (int c = 0; c < NCHUNK; ++c) {
        ms[c] = mstat[((c * H_HEADS + h) << 9) + m];
        mg = fmaxf(mg, ms[c]);
    }
    float denom = 0.f, o0 = 0.f, o1 = 0.f;
#pragma unroll
    for (int c = 0; c < NCHUNK; ++c) {
        float e = __expf(ms[c] - mg);
        denom += lstat[((c * H_HEADS + h) << 9) + m] * e;
        const float* Oc = Opart + (((size_t)(c * H_HEADS + h) << 9) + m) * D_HEAD + d;
        float2 v = *(const float2*)Oc;
        o0 += v.x * e;
        o1 += v.y * e;
    }
    float inv = 1.0f / denom;
    float* op = out + (size_t)m * N_DIM + h * D_HEAD + d;
    op[0] = o0 * inv;
    op[1] = o1 * inv;
}

// ---------------------------------------------------------------------------
extern "C" void kernel_launch(void* const* d_in, const int* in_sizes, int n_in,
                              void* d_out, int out_size, void* d_ws, size_t ws_size,
                              hipStream_t stream) {
    const float* X = (const float*)d_in[0];
    const float* W = (const float*)d_in[1];
    const float* cK = (const float*)d_in[2];
    const float* cV = (const float*)d_in[3];
    const int* Pp = (const int*)d_in[4];
    float* out = (float*)d_out;

    char* ws = (char*)d_ws;
    // workspace layout (bytes):
    //   Q16    @ 0           (2,097,152)
    //   K16    @ 2,097,152   (16,777,216)
    //   V16T   @ 18,874,368  (16,777,216)
    //   W16T   @ 35,651,584  (25,165,824)  [dead after gemm_fused]
    //   Vnew16 @ 60,817,408  (2,097,152)   [dead after transpose_vnew]
    //   Opart  @ 35,651,584  (33,554,432)  [overlays W16T+Vnew16, both dead]
    //   mstat  @ 69,206,016  (262,144)
    //   lstat  @ 69,468,160  (262,144)
    //   total 69,730,304
    half_t* Q16 = (half_t*)(ws + 0);
    half_t* K16 = (half_t*)(ws + 2097152);
    half_t* V16T = (half_t*)(ws + 18874368);
    half_t* W16T = (half_t*)(ws + 35651584);
    half_t* Vnew16 = (half_t*)(ws + 60817408);
    float* Opart = (float*)(ws + 35651584);
    float* mstat = (float*)(ws + 69206016);
    float* lstat = (float*)(ws + 69468160);

    convert_k_kernel<<<8192, 256, 0, stream>>>(cK, K16);
    transpose_v_kernel<<<8192, 256, 0, stream>>>(cV, V16T);
    transpose_w_kernel<<<dim3(192, 64), 256, 0, stream>>>(W, W16T);
    gemm_fused_kernel<<<dim3(48, 8), 256, 0, stream>>>(X, W16T, Pp, Q16, K16, Vnew16);
    transpose_vnew_kernel<<<1024, 256, 0, stream>>>(Vnew16, Pp, V16T);
    attn_partial_kernel<<<dim3(4, 16, 8), 256, 0, stream>>>(Q16, K16, V16T, Opart, mstat, lstat);
    combine_kernel<<<2048, 256, 0, stream>>>(Opart, mstat, lstat, out);
}

// Round 5
// 242.019 us; speedup vs baseline: 2.2297x; 1.1396x over previous
//
#include <hip/hip_runtime.h>
#include <math.h>

typedef _Float16 half_t;
typedef _Float16 half8 __attribute__((ext_vector_type(8)));
typedef _Float16 half4_t __attribute__((ext_vector_type(4)));
typedef _Float16 half2_t __attribute__((ext_vector_type(2)));
typedef float floatx4 __attribute__((ext_vector_type(4)));

#define M_TOK 512
#define N_DIM 2048
#define D_HEAD 128
#define H_HEADS 16
#define L_CACHE 4096
#define THREE_N 6144
#define NCHUNK 16
#define LCHUNK 256

// ---------------------------------------------------------------------------
// Kernel 1: merged prep. Regions by blockIdx.x:
//   [0,8192)        convert cache_K fp32 -> K16 fp16 (same [H,L,D] layout)
//   [8192,9216)     convert X fp32 -> X16 fp16
//   [9216,17408)    transpose cache_V [H,L,D] fp32 -> V16T [H,D,L] fp16
//   [17408,29696)   transpose W [K,N3] fp32 -> W16T [N3,K] fp16
// ---------------------------------------------------------------------------
__global__ __launch_bounds__(256) void prep_kernel(const float* __restrict__ cK,
                                                   const float* __restrict__ cV,
                                                   const float* __restrict__ W,
                                                   const float* __restrict__ X,
                                                   half_t* __restrict__ K16,
                                                   half_t* __restrict__ V16T,
                                                   half_t* __restrict__ W16T,
                                                   half_t* __restrict__ X16) {
    __shared__ half_t tile[32 * 36];
    int b = blockIdx.x;
    int t = threadIdx.x;

    if (b < 8192) {  // convert K
        size_t i = ((size_t)b * 256 + t) * 4;
        float4 v = *(const float4*)(cK + i);
        half4_t h = {(half_t)v.x, (half_t)v.y, (half_t)v.z, (half_t)v.w};
        *(half4_t*)(K16 + i) = h;
        return;
    }
    b -= 8192;
    if (b < 1024) {  // convert X
        size_t i = ((size_t)b * 256 + t) * 4;
        float4 v = *(const float4*)(X + i);
        half4_t h = {(half_t)v.x, (half_t)v.y, (half_t)v.z, (half_t)v.w};
        *(half4_t*)(X16 + i) = h;
        return;
    }
    b -= 1024;
    if (b < 8192) {  // transpose V: 32(l) x 32(d) tiles
        int h = b >> 9;
        int rem = b & 511;
        int lt = rem >> 2, dt = rem & 3;
        int l0 = lt * 32, d0 = dt * 32;
        {
            int li = t >> 3, c4 = (t & 7) * 4;
            float4 v = *(const float4*)(cV + ((size_t)h * L_CACHE + l0 + li) * D_HEAD + d0 + c4);
            tile[li * 36 + c4 + 0] = (half_t)v.x;
            tile[li * 36 + c4 + 1] = (half_t)v.y;
            tile[li * 36 + c4 + 2] = (half_t)v.z;
            tile[li * 36 + c4 + 3] = (half_t)v.w;
        }
        __syncthreads();
        {
            int di = t >> 3, lj = (t & 7) * 4;
            half4_t o = {tile[(lj + 0) * 36 + di], tile[(lj + 1) * 36 + di],
                         tile[(lj + 2) * 36 + di], tile[(lj + 3) * 36 + di]};
            *(half4_t*)(V16T + ((size_t)h * D_HEAD + d0 + di) * L_CACHE + l0 + lj) = o;
        }
        return;
    }
    b -= 8192;
    {  // transpose W: 32(k) x 32(n) tiles, b in [0,12288)
        int n0 = (b % 192) * 32, k0 = (b / 192) * 32;
        {
            int ki = t >> 3, n4 = (t & 7) * 4;
            float4 v = *(const float4*)(W + (size_t)(k0 + ki) * THREE_N + n0 + n4);
            tile[ki * 36 + n4 + 0] = (half_t)v.x;
            tile[ki * 36 + n4 + 1] = (half_t)v.y;
            tile[ki * 36 + n4 + 2] = (half_t)v.z;
            tile[ki * 36 + n4 + 3] = (half_t)v.w;
        }
        __syncthreads();
        {
            int ni = t >> 3, k4 = (t & 7) * 4;
            half4_t o = {tile[(k4 + 0) * 36 + ni], tile[(k4 + 1) * 36 + ni],
                         tile[(k4 + 2) * 36 + ni], tile[(k4 + 3) * 36 + ni]};
            *(half4_t*)(W16T + (size_t)(n0 + ni) * N_DIM + k0 + k4) = o;
        }
    }
}

// ---------------------------------------------------------------------------
// Kernel 2: fused GEMM + RMS-norm + scatter (incl. direct V^T write).
// Tile = X16[64m x 2048] @ W16T[128n x 2048]^T. bx 0..15 q-head, 16..31
// k-head (-> K16 rows P..P+M, fp16), 32..47 v-head (-> V16T via LDS transpose).
// ---------------------------------------------------------------------------
__global__ __launch_bounds__(256) void gemm_fused_kernel(const half_t* __restrict__ X16,
                                                         const half_t* __restrict__ W16T,
                                                         const int* __restrict__ Pp,
                                                         half_t* __restrict__ Q16,
                                                         half_t* __restrict__ K16,
                                                         half_t* __restrict__ V16T) {
    __shared__ half_t As[64 * 72];   // [m][k] BK=64
    __shared__ half_t Bs[128 * 72];  // [n][k]
    __shared__ half_t Vt[128 * 72];  // epilogue transpose buffer (seg 2)
    __shared__ float ssbuf[4][32];
    const int t = threadIdx.x;
    const int wid = t >> 6, lane = t & 63;
    const int quad = lane >> 4, ln = lane & 15;
    const int bx = blockIdx.x, by = blockIdx.y;
    const int m0 = by * 64, n0 = bx * 128;
    const int wm = (wid >> 1) * 32, wn = (wid & 1) * 64;

    floatx4 acc[2][4] = {};

    const int ar = t >> 3, ag = (t & 7) * 8;  // A: 32 rows/pass, 2 passes
    const int br = t >> 3, bg = (t & 7) * 8;  // B: 32 rows/pass, 4 passes

    for (int k0 = 0; k0 < N_DIM; k0 += 64) {
        __syncthreads();
#pragma unroll
        for (int p = 0; p < 2; ++p) {
            int r = ar + p * 32;
            *(half8*)&As[r * 72 + ag] =
                *(const half8*)(X16 + (size_t)(m0 + r) * N_DIM + k0 + ag);
        }
#pragma unroll
        for (int p = 0; p < 4; ++p) {
            int r = br + p * 32;
            *(half8*)&Bs[r * 72 + bg] =
                *(const half8*)(W16T + (size_t)(n0 + r) * N_DIM + k0 + bg);
        }
        __syncthreads();
#pragma unroll
        for (int kt = 0; kt < 2; ++kt) {
            half8 a[2], b[4];
#pragma unroll
            for (int i = 0; i < 2; ++i)
                a[i] = *(half8*)&As[(wm + i * 16 + ln) * 72 + kt * 32 + quad * 8];
#pragma unroll
            for (int j = 0; j < 4; ++j)
                b[j] = *(half8*)&Bs[(wn + j * 16 + ln) * 72 + kt * 32 + quad * 8];
#pragma unroll
            for (int i = 0; i < 2; ++i)
#pragma unroll
                for (int j = 0; j < 4; ++j)
                    acc[i][j] = __builtin_amdgcn_mfma_f32_16x16x32_f16(a[i], b[j], acc[i][j], 0, 0, 0);
        }
    }

    const int seg = bx >> 4, h = bx & 15;
    const int P = *Pp;

    if (seg < 2) {  // q or k: RMS-norm then write
        float ss[2][4], scale[2][4];
#pragma unroll
        for (int i = 0; i < 2; ++i)
#pragma unroll
            for (int r = 0; r < 4; ++r) {
                float s = 0.f;
#pragma unroll
                for (int j = 0; j < 4; ++j) s += acc[i][j][r] * acc[i][j][r];
#pragma unroll
                for (int msk = 1; msk < 16; msk <<= 1) s += __shfl_xor(s, msk, 64);
                ss[i][r] = s;
            }
        if (ln == 0) {
#pragma unroll
            for (int i = 0; i < 2; ++i)
#pragma unroll
                for (int r = 0; r < 4; ++r)
                    ssbuf[wid][i * 16 + quad * 4 + r] = ss[i][r];
        }
        __syncthreads();
#pragma unroll
        for (int i = 0; i < 2; ++i)
#pragma unroll
            for (int r = 0; r < 4; ++r)
                scale[i][r] =
                    rsqrtf((ss[i][r] + ssbuf[wid ^ 1][i * 16 + quad * 4 + r]) * (1.0f / 128.0f));
#pragma unroll
        for (int i = 0; i < 2; ++i) {
            int mbase = m0 + wm + i * 16 + quad * 4;
#pragma unroll
            for (int j = 0; j < 4; ++j) {
                int col = wn + j * 16 + ln;
#pragma unroll
                for (int r = 0; r < 4; ++r) {
                    int m = mbase + r;
                    half_t val = (half_t)(acc[i][j][r] * scale[i][r]);
                    if (seg == 0)
                        Q16[((size_t)h * M_TOK + m) * D_HEAD + col] = val;
                    else
                        K16[((size_t)h * L_CACHE + P + m) * D_HEAD + col] = val;
                }
            }
        }
    } else {  // v: transpose via LDS, write V^T columns (coalesced 16B stores)
#pragma unroll
        for (int i = 0; i < 2; ++i) {
            int mbase = wm + i * 16 + quad * 4;
#pragma unroll
            for (int j = 0; j < 4; ++j) {
                int d = wn + j * 16 + ln;
#pragma unroll
                for (int r = 0; r < 4; ++r)
                    Vt[d * 72 + mbase + r] = (half_t)acc[i][j][r];
            }
        }
        __syncthreads();
#pragma unroll
        for (int p = 0; p < 4; ++p) {
            int s = p * 256 + t;
            int d = s >> 3, sg = s & 7;
            *(half8*)(V16T + ((size_t)h * D_HEAD + d) * L_CACHE + P + m0 + sg * 8) =
                *(half8*)&Vt[d * 72 + sg * 8];
        }
    }
}

// ---------------------------------------------------------------------------
// Kernel 3: flash attention partial over L-chunk of 256. grid (4, H, NCHUNK),
// 128 m-rows per block: 4 waves x 2 strips of 16 rows. Online softmax,
// unnormalized fp16 partial O + (m,l) stats.
// ---------------------------------------------------------------------------
__global__ __launch_bounds__(256) void attn_partial_kernel(const half_t* __restrict__ Q16,
                                                           const half_t* __restrict__ K16,
                                                           const half_t* __restrict__ V16T,
                                                           half_t* __restrict__ Opart,
                                                           float* __restrict__ mstat,
                                                           float* __restrict__ lstat) {
    __shared__ half_t Ks[64 * 136];
    __shared__ half_t Vs[128 * 72];
    __shared__ half_t Ps[4 * 16 * 72];
    const int t = threadIdx.x, w = t >> 6, lane = t & 63;
    const int quad = lane >> 4, ln = lane & 15;
    const int h = blockIdx.y, c = blockIdx.z;
    const int mb = blockIdx.x * 128;
    const half_t* Qh = Q16 + (size_t)h * M_TOK * D_HEAD;
    const half_t* Kh = K16 + (size_t)h * L_CACHE * D_HEAD;
    const half_t* Vh = V16T + (size_t)h * D_HEAD * L_CACHE;

    half8 qf[2][4];
#pragma unroll
    for (int s = 0; s < 2; ++s) {
        int m0 = mb + s * 64 + w * 16;
#pragma unroll
        for (int dt = 0; dt < 4; ++dt)
            qf[s][dt] = *(const half8*)(Qh + (size_t)(m0 + ln) * D_HEAD + dt * 32 + quad * 8);
    }

    floatx4 oacc[2][8] = {};
    float mrow[2][4], lrow[2][4];
#pragma unroll
    for (int s = 0; s < 2; ++s)
#pragma unroll
        for (int r = 0; r < 4; ++r) { mrow[s][r] = -INFINITY; lrow[s][r] = 0.f; }

    half_t* Pw = Ps + w * (16 * 72);

    for (int l0 = c * LCHUNK; l0 < (c + 1) * LCHUNK; l0 += 64) {
        __syncthreads();
        {
            int lr = t >> 4, ch = t & 15;
#pragma unroll
            for (int p = 0; p < 4; ++p, lr += 16)
                *(half8*)&Ks[lr * 136 + ch * 8] =
                    *(const half8*)(Kh + (size_t)(l0 + lr) * D_HEAD + ch * 8);
        }
        {
            int dr = t >> 3, ch = t & 7;
#pragma unroll
            for (int p = 0; p < 4; ++p, dr += 32)
                *(half8*)&Vs[dr * 72 + ch * 8] =
                    *(const half8*)(Vh + (size_t)dr * L_CACHE + l0 + ch * 8);
        }
        __syncthreads();

#pragma unroll
        for (int s = 0; s < 2; ++s) {
            floatx4 sacc[4] = {};
#pragma unroll
            for (int nt = 0; nt < 4; ++nt)
#pragma unroll
                for (int dt = 0; dt < 4; ++dt) {
                    half8 b = *(half8*)&Ks[(nt * 16 + ln) * 136 + dt * 32 + quad * 8];
                    sacc[nt] = __builtin_amdgcn_mfma_f32_16x16x32_f16(qf[s][dt], b, sacc[nt], 0, 0, 0);
                }

            float alpha[4];
#pragma unroll
            for (int r = 0; r < 4; ++r) {
                float mx = fmaxf(fmaxf(sacc[0][r], sacc[1][r]), fmaxf(sacc[2][r], sacc[3][r]));
#pragma unroll
                for (int msk = 8; msk; msk >>= 1) mx = fmaxf(mx, __shfl_xor(mx, msk, 16));
                float mnew = fmaxf(mrow[s][r], mx);
                alpha[r] = __expf(mrow[s][r] - mnew);
                mrow[s][r] = mnew;
                float psum = 0.f;
#pragma unroll
                for (int nt = 0; nt < 4; ++nt) {
                    float p = __expf(sacc[nt][r] - mnew);
                    sacc[nt][r] = p;
                    psum += p;
                }
#pragma unroll
                for (int msk = 8; msk; msk >>= 1) psum += __shfl_xor(psum, msk, 16);
                lrow[s][r] = lrow[s][r] * alpha[r] + psum;
            }

#pragma unroll
            for (int nt = 0; nt < 4; ++nt)
#pragma unroll
                for (int r = 0; r < 4; ++r)
                    Pw[(quad * 4 + r) * 72 + nt * 16 + ln] = (half_t)sacc[nt][r];

#pragma unroll
            for (int nt8 = 0; nt8 < 8; ++nt8)
#pragma unroll
                for (int r = 0; r < 4; ++r)
                    oacc[s][nt8][r] *= alpha[r];

#pragma unroll
            for (int kt = 0; kt < 2; ++kt) {
                half8 a = *(half8*)&Pw[ln * 72 + kt * 32 + quad * 8];
#pragma unroll
                for (int nt8 = 0; nt8 < 8; ++nt8) {
                    half8 b = *(half8*)&Vs[(nt8 * 16 + ln) * 72 + kt * 32 + quad * 8];
                    oacc[s][nt8] = __builtin_amdgcn_mfma_f32_16x16x32_f16(a, b, oacc[s][nt8], 0, 0, 0);
                }
            }
        }
    }

    half_t* Oc = Opart + ((size_t)(c * H_HEADS + h) * M_TOK) * D_HEAD;
    float* ms = mstat + (size_t)(c * H_HEADS + h) * M_TOK;
    float* ls = lstat + (size_t)(c * H_HEADS + h) * M_TOK;
#pragma unroll
    for (int s = 0; s < 2; ++s) {
        int m0 = mb + s * 64 + w * 16;
#pragma unroll
        for (int nt8 = 0; nt8 < 8; ++nt8) {
            int col = nt8 * 16 + ln;
#pragma unroll
            for (int r = 0; r < 4; ++r)
                Oc[(size_t)(m0 + quad * 4 + r) * D_HEAD + col] = (half_t)oacc[s][nt8][r];
        }
        if (ln == 0) {
#pragma unroll
            for (int r = 0; r < 4; ++r) {
                ms[m0 + quad * 4 + r] = mrow[s][r];
                ls[m0 + quad * 4 + r] = lrow[s][r];
            }
        }
    }
}

// ---------------------------------------------------------------------------
// Kernel 4: combine NCHUNK fp16 partials. One wave per (h,m) row.
// ---------------------------------------------------------------------------
__global__ __launch_bounds__(256) void combine_kernel(const half_t* __restrict__ Opart,
                                                      const float* __restrict__ mstat,
                                                      const float* __restrict__ lstat,
                                                      float* __restrict__ out) {
    int gw = blockIdx.x * 4 + (threadIdx.x >> 6);
    int lane = threadIdx.x & 63;
    int h = gw >> 9, m = gw & 511;
    int d = lane * 2;

    float ms[NCHUNK];
    float mg = -INFINITY;
#pragma unroll
    for (int c = 0; c < NCHUNK; ++c) {
        ms[c] = mstat[((c * H_HEADS + h) << 9) + m];
        mg = fmaxf(mg, ms[c]);
    }
    float denom = 0.f, o0 = 0.f, o1 = 0.f;
#pragma unroll
    for (int c = 0; c < NCHUNK; ++c) {
        float e = __expf(ms[c] - mg);
        denom += lstat[((c * H_HEADS + h) << 9) + m] * e;
        const half_t* Oc = Opart + (((size_t)(c * H_HEADS + h) << 9) + m) * D_HEAD + d;
        half2_t v = *(const half2_t*)Oc;
        o0 += (float)v.x * e;
        o1 += (float)v.y * e;
    }
    float inv = 1.0f / denom;
    float* op = out + (size_t)m * N_DIM + h * D_HEAD + d;
    op[0] = o0 * inv;
    op[1] = o1 * inv;
}

// ---------------------------------------------------------------------------
extern "C" void kernel_launch(void* const* d_in, const int* in_sizes, int n_in,
                              void* d_out, int out_size, void* d_ws, size_t ws_size,
                              hipStream_t stream) {
    const float* X = (const float*)d_in[0];
    const float* W = (const float*)d_in[1];
    const float* cK = (const float*)d_in[2];
    const float* cV = (const float*)d_in[3];
    const int* Pp = (const int*)d_in[4];
    float* out = (float*)d_out;

    char* ws = (char*)d_ws;
    // workspace layout (bytes):
    //   Q16    @ 0           (2,097,152)
    //   K16    @ 2,097,152   (16,777,216)
    //   V16T   @ 18,874,368  (16,777,216)
    //   X16    @ 35,651,584  (2,097,152)
    //   W16T   @ 37,748,736  (25,165,824)  [dead after gemm_fused]
    //   Opart16@ 37,748,736  (33,554,432 = NCHUNK(16)*16*512*128*2) [overlays W16T]
    //   mstat  @ 71,303,168  (524,288)     <- past Opart end (R4 bug: was inside Opart)
    //   lstat  @ 71,827,456  (524,288)
    //   total 72,351,744
    half_t* Q16 = (half_t*)(ws + 0);
    half_t* K16 = (half_t*)(ws + 2097152);
    half_t* V16T = (half_t*)(ws + 18874368);
    half_t* X16 = (half_t*)(ws + 35651584);
    half_t* W16T = (half_t*)(ws + 37748736);
    half_t* Opart = (half_t*)(ws + 37748736);
    float* mstat = (float*)(ws + 71303168);
    float* lstat = (float*)(ws + 71827456);

    prep_kernel<<<29696, 256, 0, stream>>>(cK, cV, W, X, K16, V16T, W16T, X16);
    gemm_fused_kernel<<<dim3(48, 8), 256, 0, stream>>>(X16, W16T, Pp, Q16, K16, V16T);
    attn_partial_kernel<<<dim3(4, 16, NCHUNK), 256, 0, stream>>>(Q16, K16, V16T, Opart, mstat, lstat);
    combine_kernel<<<2048, 256, 0, stream>>>(Opart, mstat, lstat, out);
}